// Round 2
// baseline (226.152 us; speedup 1.0000x reference)
//
#include <hip/hip_runtime.h>
#include <hip/hip_bf16.h>

#define N_NODES 50000
#define N_EDGES 800000
#define DIM 256      // input feature dim = K
#define QKDIM 256    // packed q|k per node (fp8: 256 B/row)
// pre = (0.5/H) * sum_A (q_s k_d + q_d k_s) = (full rotated 256-dot)/16

typedef __bf16 bfrag  __attribute__((ext_vector_type(8)));
typedef __bf16 bf4    __attribute__((ext_vector_type(4)));
typedef float  ffrag  __attribute__((ext_vector_type(4)));
typedef float  f2     __attribute__((ext_vector_type(2)));
typedef float  f4v    __attribute__((ext_vector_type(4)));

#define EP_PITCH 272   // epilogue LDS byte pitch (256+16)

// ---------------- prep: W' fp32->bf16 + zero diagA0 region ----------------
__global__ __launch_bounds__(256) void prep_kernel(
    const float* __restrict__ Wq, const float* __restrict__ Wk,
    __bf16* __restrict__ Wb, float* __restrict__ out)
{
    const int tid = blockIdx.x * 256 + threadIdx.x;   // 0..16383
    const int i = tid * 4;                            // 65536 elems total
    const float* s = (i < 32768) ? (Wq + i) : (Wk + (i - 32768));
    const float4 v = *(const float4*)s;
    bf4 o;
    o[0] = (__bf16)v.x; o[1] = (__bf16)v.y; o[2] = (__bf16)v.z; o[3] = (__bf16)v.w;
    *(bf4*)(Wb + i) = o;

    if (i + 4 <= N_NODES)   // 50000 % 4 == 0, covers exactly
        *(float4*)(out + i) = make_float4(0.f, 0.f, 0.f, 0.f);
}

// ---------------- Projection via MFMA bf16 ----------------
// Block: 64 nodes x 256 cols, 4 waves; wave wv covers cols [64wv, 64wv+64).
// A staged in LDS in fragment order; B preloaded to regs per K-half;
// epilogue via LDS transpose -> coalesced dwordx4 stores.
__global__ __launch_bounds__(256) void proj_mfma(
    const float* __restrict__ x,
    const __bf16* __restrict__ Wb,
    const float* __restrict__ bq, const float* __restrict__ bk,
    unsigned char* __restrict__ qk8)
{
    __shared__ __bf16 As[64 * 256];   // 32 KB, fragment-order; reused by epilogue

    const int tid  = threadIdx.x;
    const int wv   = tid >> 6;         // 0..3 -> 64-col slice
    const int lane = tid & 63;
    const int m    = lane & 15;
    const int q    = lane >> 4;
    const int mbase = blockIdx.x * 64;

    // ---- stage A (64 rows x 256 k fp32 -> bf16 frags) ----
    {
        const int srow = tid >> 2;           // 0..63
        const int c4   = tid & 3;
        int grow = mbase + srow;
        grow = grow < N_NODES ? grow : N_NODES - 1;
        const float* xp = x + (size_t)grow * DIM;
        const int mt_ = srow >> 4, m_ = srow & 15;
        #pragma unroll
        for (int i = 0; i < 16; ++i) {
            const int k = c4 * 4 + 16 * i;
            // x is stream-once: nontemporal keeps it from evicting L2 working set
            const f4v v = __builtin_nontemporal_load((const f4v*)(xp + k));
            bf4 o;
            o[0] = (__bf16)v[0]; o[1] = (__bf16)v[1];
            o[2] = (__bf16)v[2]; o[3] = (__bf16)v[3];
            const int seg = (k >> 5) * 4 + mt_;
            const int ln  = ((k >> 3) & 3) * 16 + m_;
            *(bf4*)(As + seg * 512 + ln * 8 + (k & 7)) = o;
        }
    }
    __syncthreads();

    ffrag acc[4][4] = {};              // [m-tile][n-tile]

    #pragma unroll
    for (int h = 0; h < 2; ++h) {
        // preload this K-half's B fragments (16 dwordx4, L2-hit, independent)
        bfrag b[4][4];                 // [k-step][n-tile]
        #pragma unroll
        for (int sp = 0; sp < 4; ++sp)
            #pragma unroll
            for (int nt = 0; nt < 4; ++nt) {
                const int col = wv * 64 + nt * 16 + m;
                b[sp][nt] = *(const bfrag*)(Wb + (size_t)col * DIM
                                            + 32 * (4 * h + sp) + 8 * q);
            }
        #pragma unroll
        for (int sp = 0; sp < 4; ++sp) {
            bfrag a[4];
            #pragma unroll
            for (int mt = 0; mt < 4; ++mt)
                a[mt] = *(const bfrag*)(As + ((4 * h + sp) * 4 + mt) * 512 + lane * 8);
            #pragma unroll
            for (int mt = 0; mt < 4; ++mt)
                #pragma unroll
                for (int nt = 0; nt < 4; ++nt)
                    acc[mt][nt] = __builtin_amdgcn_mfma_f32_16x16x32_bf16(
                                      a[mt], b[sp][nt], acc[mt][nt], 0, 0, 0);
        }
    }

    // ---- epilogue: fp8-encode into LDS (transpose), then coalesced stores
    __syncthreads();                    // all waves done reading As
    unsigned char* ep = (unsigned char*)As;   // [64][EP_PITCH] bytes, 17 KB
    #pragma unroll
    for (int nt = 0; nt < 4; ++nt) {
        const int col  = wv * 64 + nt * 16 + m;
        const float bias = (col < 128) ? bq[col] : bk[col - 128];
        #pragma unroll
        for (int mt = 0; mt < 4; ++mt) {
            #pragma unroll
            for (int r = 0; r < 4; ++r) {
                const int rl = mt * 16 + q * 4 + r;
                const float v = acc[mt][nt][r] + bias;
                const int pk = __builtin_amdgcn_cvt_pk_fp8_f32(v, v, 0, false);
                ep[rl * EP_PITCH + col] = (unsigned char)(pk & 0xFF);
            }
        }
    }
    __syncthreads();
    {
        const int rl = tid >> 2;              // 0..63
        const int ch = tid & 3;               // 64-B chunk
        const int grow = mbase + rl;
        if (grow < N_NODES) {
            const uint4* s4 = (const uint4*)(ep + rl * EP_PITCH + ch * 64);
            const uint4 t0 = s4[0], t1 = s4[1], t2 = s4[2], t3 = s4[3];
            uint4* g = (uint4*)(qk8 + (size_t)grow * QKDIM + ch * 64);
            g[0] = t0; g[1] = t1; g[2] = t2; g[3] = t3;
        }
    }
}

// ---------------- Edge scoring + scatter (fp8 gather) ----------------
// 4 lanes per edge-slot, 16 slots per wave, TWO edges per slot (e, e+16).
// All 16 gathers issued up-front -> 2x memory-level parallelism in the
// latency-bound regime. Lane j covers src bytes [64j, +64); dst bytes
// 64*((j+2)&3) (the (t+128)&255 q|k rotation).  [R4 known-good rotation]
__global__ __launch_bounds__(256) void edge_kernel(
    const unsigned char* __restrict__ qk8,
    const int* __restrict__ edge_index,   // [2][E]
    const int* __restrict__ d0,           // d0_index row 1, [2E]
    float* __restrict__ out)              // [0..N)=diagA0 (pre-zeroed), [N..N+E)=diagA1
{
    const int wave = (blockIdx.x * blockDim.x + threadIdx.x) >> 6;
    const int lane = threadIdx.x & 63;
    const int g = lane >> 2;              // edge slot within wave (0..15)
    const int j = lane & 3;               // lane within edge
    const int e0 = wave * 32 + g;         // 800000 = 25000*32, no tail
    const int e1 = e0 + 16;

    // indices are stream-once: nontemporal keeps qk8 gather set resident in L2
    const int src0 = __builtin_nontemporal_load(edge_index + e0);
    const int dst0 = __builtin_nontemporal_load(edge_index + N_EDGES + e0);
    const int src1 = __builtin_nontemporal_load(edge_index + e1);
    const int dst1 = __builtin_nontemporal_load(edge_index + N_EDGES + e1);

    // hoist scatter targets so their loads overlap the gathers/compute
    int t0 = 0, t1 = 0;
    if (j < 2) {
        t0 = __builtin_nontemporal_load(d0 + 2 * e0 + j);
        t1 = __builtin_nontemporal_load(d0 + 2 * e1 + j);
    }

    const uint4* rs0 = (const uint4*)(qk8 + (size_t)src0 * QKDIM + 64 * j);
    const uint4* rd0 = (const uint4*)(qk8 + (size_t)dst0 * QKDIM + 64 * ((j + 2) & 3));
    const uint4* rs1 = (const uint4*)(qk8 + (size_t)src1 * QKDIM + 64 * j);
    const uint4* rd1 = (const uint4*)(qk8 + (size_t)dst1 * QKDIM + 64 * ((j + 2) & 3));

    uint4 a0[4], b0[4], a1[4], b1[4];
    #pragma unroll
    for (int i = 0; i < 4; ++i) { a0[i] = rs0[i]; b0[i] = rd0[i]; }
    #pragma unroll
    for (int i = 0; i < 4; ++i) { a1[i] = rs1[i]; b1[i] = rd1[i]; }

    // packed-f32 accumulation: pairs feed v_pk_fma_f32 (half the FMA instrs)
    f2 acc0 = {0.f, 0.f};
    #pragma unroll
    for (int i = 0; i < 4; ++i) {
        const unsigned int* ua = (const unsigned int*)&a0[i];
        const unsigned int* ub = (const unsigned int*)&b0[i];
        #pragma unroll
        for (int t = 0; t < 4; ++t) {
            const f2 x0 = __builtin_amdgcn_cvt_pk_f32_fp8(ua[t], false);
            const f2 y0 = __builtin_amdgcn_cvt_pk_f32_fp8(ub[t], false);
            const f2 x1 = __builtin_amdgcn_cvt_pk_f32_fp8(ua[t], true);
            const f2 y1 = __builtin_amdgcn_cvt_pk_f32_fp8(ub[t], true);
            acc0 += x0 * y0;
            acc0 += x1 * y1;
        }
    }
    float p0 = acc0[0] + acc0[1];
    p0 += __shfl_xor(p0, 1, 64);
    p0 += __shfl_xor(p0, 2, 64);

    f2 acc1 = {0.f, 0.f};
    #pragma unroll
    for (int i = 0; i < 4; ++i) {
        const unsigned int* ua = (const unsigned int*)&a1[i];
        const unsigned int* ub = (const unsigned int*)&b1[i];
        #pragma unroll
        for (int t = 0; t < 4; ++t) {
            const f2 x0 = __builtin_amdgcn_cvt_pk_f32_fp8(ua[t], false);
            const f2 y0 = __builtin_amdgcn_cvt_pk_f32_fp8(ub[t], false);
            const f2 x1 = __builtin_amdgcn_cvt_pk_f32_fp8(ua[t], true);
            const f2 y1 = __builtin_amdgcn_cvt_pk_f32_fp8(ub[t], true);
            acc1 += x0 * y0;
            acc1 += x1 * y1;
        }
    }
    float p1 = acc1[0] + acc1[1];
    p1 += __shfl_xor(p1, 1, 64);
    p1 += __shfl_xor(p1, 2, 64);

    if (j < 2) {
        const float v0 = __expf(p0 * 0.0625f);   // /16 = 0.5 * mean over 8 heads
        if (j == 0) __builtin_nontemporal_store(v0, out + N_NODES + e0);  // diagA1
        atomicAdd(&out[t0], v0);
        const float v1 = __expf(p1 * 0.0625f);
        if (j == 0) __builtin_nontemporal_store(v1, out + N_NODES + e1);
        atomicAdd(&out[t1], v1);
    }
}

extern "C" void kernel_launch(void* const* d_in, const int* in_sizes, int n_in,
                              void* d_out, int out_size, void* d_ws, size_t ws_size,
                              hipStream_t stream) {
    const float* x  = (const float*)d_in[0];
    const float* Wq = (const float*)d_in[1];
    const float* bq = (const float*)d_in[2];
    const float* Wk = (const float*)d_in[3];
    const float* bk = (const float*)d_in[4];
    const int* edge_index = (const int*)d_in[5];
    const int* d0 = (const int*)d_in[6] + 2 * N_EDGES;  // row 1 of d0_index
    float* out = (float*)d_out;

    unsigned char* qk8 = (unsigned char*)d_ws;                       // 12.8 MB
    __bf16* Wb = (__bf16*)((char*)d_ws + (size_t)N_NODES * QKDIM);   // +128 KB

    prep_kernel<<<64, 256, 0, stream>>>(Wq, Wk, Wb, out);
    proj_mfma<<<(N_NODES + 63) / 64, 256, 0, stream>>>(x, Wb, bq, bk, qk8);

    // 32 edges/wave (2 per slot), 4 waves/block -> 128 edges/block
    edge_kernel<<<N_EDGES / 128, 256, 0, stream>>>(qk8, edge_index, d0, out);
}

// Round 3
// 216.421 us; speedup vs baseline: 1.0450x; 1.0450x over previous
//
#include <hip/hip_runtime.h>
#include <hip/hip_bf16.h>

#define N_NODES 50000
#define N_EDGES 800000
#define DIM 256      // input feature dim = K
#define QKDIM 256    // packed q|k per node (fp8: 256 B/row)
#define N_COPIES 8   // replicated diagA0 accumulators (atomic de-contention)
// pre = (0.5/H) * sum_A (q_s k_d + q_d k_s) = (full rotated 256-dot)/16

typedef __bf16 bfrag  __attribute__((ext_vector_type(8)));
typedef __bf16 bf4    __attribute__((ext_vector_type(4)));
typedef float  ffrag  __attribute__((ext_vector_type(4)));
typedef float  f2     __attribute__((ext_vector_type(2)));
typedef float  f4v    __attribute__((ext_vector_type(4)));

#define EP_PITCH 272   // epilogue LDS byte pitch (256+16)

// ---------------- prep: W' fp32->bf16 + zero accumulator region ----------------
// flag=1: zero priv[N_COPIES][N_NODES] (reduce overwrites out later)
// flag=0: zero out[0..N) (fallback, atomics go directly to out)
__global__ __launch_bounds__(256) void prep_kernel(
    const float* __restrict__ Wq, const float* __restrict__ Wk,
    __bf16* __restrict__ Wb, float* __restrict__ out,
    float* __restrict__ priv, int flag)
{
    const int tid = blockIdx.x * 256 + threadIdx.x;
    const int i = tid * 4;
    if (i < 65536) {
        const float* s = (i < 32768) ? (Wq + i) : (Wk + (i - 32768));
        const float4 v = *(const float4*)s;
        bf4 o;
        o[0] = (__bf16)v.x; o[1] = (__bf16)v.y; o[2] = (__bf16)v.z; o[3] = (__bf16)v.w;
        *(bf4*)(Wb + i) = o;
    }
    if (flag) {
        if (tid < (N_COPIES * N_NODES) / 4)   // 100000 float4s
            ((float4*)priv)[tid] = make_float4(0.f, 0.f, 0.f, 0.f);
    } else {
        if (i + 4 <= N_NODES)
            *(float4*)(out + i) = make_float4(0.f, 0.f, 0.f, 0.f);
    }
}

// ---------------- Projection via MFMA bf16 ----------------
// Block: 64 nodes x 256 cols, 4 waves; wave wv covers cols [64wv, 64wv+64).
// A staged in LDS in fragment order; B preloaded to regs per K-half;
// epilogue via LDS transpose -> coalesced dwordx4 stores.
__global__ __launch_bounds__(256) void proj_mfma(
    const float* __restrict__ x,
    const __bf16* __restrict__ Wb,
    const float* __restrict__ bq, const float* __restrict__ bk,
    unsigned char* __restrict__ qk8)
{
    __shared__ __bf16 As[64 * 256];   // 32 KB, fragment-order; reused by epilogue

    const int tid  = threadIdx.x;
    const int wv   = tid >> 6;         // 0..3 -> 64-col slice
    const int lane = tid & 63;
    const int m    = lane & 15;
    const int q    = lane >> 4;
    const int mbase = blockIdx.x * 64;

    // ---- stage A (64 rows x 256 k fp32 -> bf16 frags) ----
    {
        const int srow = tid >> 2;           // 0..63
        const int c4   = tid & 3;
        int grow = mbase + srow;
        grow = grow < N_NODES ? grow : N_NODES - 1;
        const float* xp = x + (size_t)grow * DIM;
        const int mt_ = srow >> 4, m_ = srow & 15;
        #pragma unroll
        for (int i = 0; i < 16; ++i) {
            const int k = c4 * 4 + 16 * i;
            // x is stream-once: nontemporal keeps it from evicting L2 working set
            const f4v v = __builtin_nontemporal_load((const f4v*)(xp + k));
            bf4 o;
            o[0] = (__bf16)v[0]; o[1] = (__bf16)v[1];
            o[2] = (__bf16)v[2]; o[3] = (__bf16)v[3];
            const int seg = (k >> 5) * 4 + mt_;
            const int ln  = ((k >> 3) & 3) * 16 + m_;
            *(bf4*)(As + seg * 512 + ln * 8 + (k & 7)) = o;
        }
    }
    __syncthreads();

    ffrag acc[4][4] = {};              // [m-tile][n-tile]

    #pragma unroll
    for (int h = 0; h < 2; ++h) {
        // preload this K-half's B fragments (16 dwordx4, L2-hit, independent)
        bfrag b[4][4];                 // [k-step][n-tile]
        #pragma unroll
        for (int sp = 0; sp < 4; ++sp)
            #pragma unroll
            for (int nt = 0; nt < 4; ++nt) {
                const int col = wv * 64 + nt * 16 + m;
                b[sp][nt] = *(const bfrag*)(Wb + (size_t)col * DIM
                                            + 32 * (4 * h + sp) + 8 * q);
            }
        #pragma unroll
        for (int sp = 0; sp < 4; ++sp) {
            bfrag a[4];
            #pragma unroll
            for (int mt = 0; mt < 4; ++mt)
                a[mt] = *(const bfrag*)(As + ((4 * h + sp) * 4 + mt) * 512 + lane * 8);
            #pragma unroll
            for (int mt = 0; mt < 4; ++mt)
                #pragma unroll
                for (int nt = 0; nt < 4; ++nt)
                    acc[mt][nt] = __builtin_amdgcn_mfma_f32_16x16x32_bf16(
                                      a[mt], b[sp][nt], acc[mt][nt], 0, 0, 0);
        }
    }

    // ---- epilogue: fp8-encode into LDS (transpose), then coalesced stores
    __syncthreads();                    // all waves done reading As
    unsigned char* ep = (unsigned char*)As;   // [64][EP_PITCH] bytes, 17 KB
    #pragma unroll
    for (int nt = 0; nt < 4; ++nt) {
        const int col  = wv * 64 + nt * 16 + m;
        const float bias = (col < 128) ? bq[col] : bk[col - 128];
        #pragma unroll
        for (int mt = 0; mt < 4; ++mt) {
            #pragma unroll
            for (int r = 0; r < 4; ++r) {
                const int rl = mt * 16 + q * 4 + r;
                const float v = acc[mt][nt][r] + bias;
                const int pk = __builtin_amdgcn_cvt_pk_fp8_f32(v, v, 0, false);
                ep[rl * EP_PITCH + col] = (unsigned char)(pk & 0xFF);
            }
        }
    }
    __syncthreads();
    {
        const int rl = tid >> 2;              // 0..63
        const int ch = tid & 3;               // 64-B chunk
        const int grow = mbase + rl;
        if (grow < N_NODES) {
            const uint4* s4 = (const uint4*)(ep + rl * EP_PITCH + ch * 64);
            const uint4 t0 = s4[0], t1 = s4[1], t2 = s4[2], t3 = s4[3];
            uint4* g = (uint4*)(qk8 + (size_t)grow * QKDIM + ch * 64);
            g[0] = t0; g[1] = t1; g[2] = t2; g[3] = t3;
        }
    }
}

// ---------------- Edge scoring + scatter (fp8 gather) ----------------
// 4 lanes per edge, 16 edges per wave. Lane j covers src bytes [64j, +64);
// dst bytes 64*((j+2)&3) (the (t+128)&255 q|k rotation).  [R4 known-good]
// diagA0 atomics go to accum + (blockIdx & copymask)*N_NODES: 8-way line
// replication de-contends the per-line RMW serialization at the coherence point.
__global__ __launch_bounds__(256) void edge_kernel(
    const unsigned char* __restrict__ qk8,
    const int* __restrict__ edge_index,   // [2][E]
    const int* __restrict__ d0,           // d0_index row 1, [2E]
    float* __restrict__ out,              // [N..N+E)=diagA1
    float* __restrict__ accum, int copymask)
{
    const int wave = (blockIdx.x * blockDim.x + threadIdx.x) >> 6;
    const int lane = threadIdx.x & 63;
    const int g = lane >> 2;              // edge within wave (0..15)
    const int j = lane & 3;               // lane within edge
    const int e = wave * 16 + g;          // 800000 = 50000*16, no tail

    float* myacc = accum + (size_t)(blockIdx.x & copymask) * N_NODES;

    // indices are stream-once: nontemporal keeps qk8 gather set resident in L2
    const int src = __builtin_nontemporal_load(edge_index + e);
    const int dst = __builtin_nontemporal_load(edge_index + N_EDGES + e);

    const uint4* rs = (const uint4*)(qk8 + (size_t)src * QKDIM + 64 * j);
    const uint4* rd = (const uint4*)(qk8 + (size_t)dst * QKDIM + 64 * ((j + 2) & 3));

    uint4 a[4], b[4];
    #pragma unroll
    for (int i = 0; i < 4; ++i) { a[i] = rs[i]; b[i] = rd[i]; }

    // packed-f32 accumulation: pairs feed v_pk_fma_f32 (half the FMA instrs)
    f2 acc = {0.f, 0.f};
    #pragma unroll
    for (int i = 0; i < 4; ++i) {
        const unsigned int* ua = (const unsigned int*)&a[i];
        const unsigned int* ub = (const unsigned int*)&b[i];
        #pragma unroll
        for (int t = 0; t < 4; ++t) {
            const f2 x0 = __builtin_amdgcn_cvt_pk_f32_fp8(ua[t], false);
            const f2 y0 = __builtin_amdgcn_cvt_pk_f32_fp8(ub[t], false);
            const f2 x1 = __builtin_amdgcn_cvt_pk_f32_fp8(ua[t], true);
            const f2 y1 = __builtin_amdgcn_cvt_pk_f32_fp8(ub[t], true);
            acc += x0 * y0;
            acc += x1 * y1;
        }
    }
    float p = acc[0] + acc[1];

    // reduce across the 4 lanes of this edge group
    p += __shfl_xor(p, 1, 64);
    p += __shfl_xor(p, 2, 64);

    if (j < 2) {
        const float val = __expf(p * 0.0625f);   // /16 = 0.5 * mean over 8 heads
        const int target = __builtin_nontemporal_load(d0 + 2 * e + j);
        if (j == 0) __builtin_nontemporal_store(val, out + N_NODES + e);  // diagA1
        atomicAdd(&myacc[target], val);
    }
}

// ---------------- reduce: out[n] = sum over copies of priv[c][n] ----------------
__global__ __launch_bounds__(256) void reduce_kernel(
    const float* __restrict__ priv, float* __restrict__ out)
{
    const int idx = (blockIdx.x * 256 + threadIdx.x) * 4;
    if (idx < N_NODES) {                 // N_NODES % 4 == 0, no partial vec
        f4v s = __builtin_nontemporal_load((const f4v*)(priv + idx));
        #pragma unroll
        for (int c = 1; c < N_COPIES; ++c)
            s += __builtin_nontemporal_load((const f4v*)(priv + (size_t)c * N_NODES + idx));
        *(f4v*)(out + idx) = s;
    }
}

extern "C" void kernel_launch(void* const* d_in, const int* in_sizes, int n_in,
                              void* d_out, int out_size, void* d_ws, size_t ws_size,
                              hipStream_t stream) {
    const float* x  = (const float*)d_in[0];
    const float* Wq = (const float*)d_in[1];
    const float* bq = (const float*)d_in[2];
    const float* Wk = (const float*)d_in[3];
    const float* bk = (const float*)d_in[4];
    const int* edge_index = (const int*)d_in[5];
    const int* d0 = (const int*)d_in[6] + 2 * N_EDGES;  // row 1 of d0_index
    float* out = (float*)d_out;

    unsigned char* qk8 = (unsigned char*)d_ws;                       // 12.8 MB
    __bf16* Wb = (__bf16*)((char*)d_ws + (size_t)N_NODES * QKDIM);   // +128 KB
    float* priv = (float*)((char*)d_ws + (size_t)N_NODES * QKDIM + 131072);

    const size_t needed = (size_t)N_NODES * QKDIM + 131072
                        + (size_t)N_COPIES * N_NODES * sizeof(float);
    const int use_priv = (ws_size >= needed) ? 1 : 0;
    float* accum = use_priv ? priv : out;
    const int copymask = use_priv ? (N_COPIES - 1) : 0;

    prep_kernel<<<391, 256, 0, stream>>>(Wq, Wk, Wb, out, priv, use_priv);
    proj_mfma<<<(N_NODES + 63) / 64, 256, 0, stream>>>(x, Wb, bq, bk, qk8);

    // 16 edges/wave, 4 waves/block -> 64 edges/block
    edge_kernel<<<N_EDGES / 64, 256, 0, stream>>>(qk8, edge_index, d0, out,
                                                  accum, copymask);
    if (use_priv)
        reduce_kernel<<<(N_NODES / 4 + 255) / 256, 256, 0, stream>>>(priv, out);
}